// Round 8
// baseline (415.141 us; speedup 1.0000x reference)
//
#include <hip/hip_runtime.h>
#include <stdint.h>
#include <stddef.h>

typedef __attribute__((ext_vector_type(8))) __bf16 bf16x8;
typedef __attribute__((ext_vector_type(4))) float f32x4;

#define NC 16         // s-chunks per (b,h)  (R8: 8->16 for 4 blocks/CU)
#define SCHUNK 256
#define SS 32         // s-subtile
#define NSUB 8        // SCHUNK/SS
#define KTP 256       // kT row pitch (proven layout)
#define PP 40         // P row pitch (32 + 8 pad)

#define MFMA __builtin_amdgcn_mfma_f32_16x16x32_bf16

// Raw barrier WITHOUT vmcnt(0) drain: orders LDS traffic only, leaves
// prefetched global loads in flight.
__device__ __forceinline__ void lds_barrier() {
    __builtin_amdgcn_sched_barrier(0);
    asm volatile("s_waitcnt lgkmcnt(0)" ::: "memory");
    __builtin_amdgcn_s_barrier();
    __builtin_amdgcn_sched_barrier(0);
}

// ---------------- K1: q projection -> bf16 q[bh][t][ch] in ws ----------------
__global__ __launch_bounds__(128) void k_qproj(
    const float* __restrict__ tokens, const float* __restrict__ q_w,
    const float* __restrict__ q_b, __bf16* __restrict__ ws_q)
{
    const int t = blockIdx.x >> 3;
    const int b0 = (blockIdx.x & 7) * 4;
    const int d = threadIdx.x;
    __shared__ float tok[4][128];
    #pragma unroll
    for (int j = 0; j < 4; ++j)
        tok[j][d] = tokens[((size_t)t * 32 + b0 + j) * 128 + d];
    __syncthreads();
    #pragma unroll
    for (int i = 0; i < 4; ++i) {
        const int c = d + 128 * i;
        const float* wr = q_w + (size_t)c * 128;
        const float qb = q_b[c];
        float acc[4] = {qb, qb, qb, qb};
        #pragma unroll 4
        for (int k = 0; k < 128; k += 4) {
            const float4 w4 = *(const float4*)(wr + k);
            #pragma unroll
            for (int j = 0; j < 4; ++j) {
                const float4 t4 = *(const float4*)&tok[j][k];
                acc[j] += t4.x * w4.x + t4.y * w4.y + t4.z * w4.z + t4.w * w4.w;
            }
        }
        const int h = c >> 8, cc = c & 255;
        #pragma unroll
        for (int j = 0; j < 4; ++j)
            ws_q[(size_t)(((b0 + j) * 2 + h) * 64 + t) * 256 + cc] = (__bf16)acc[j];
    }
}

// ---------------- K2: fused QK^T -> S (out) -> exp -> partial AV ----------------
// grid: 64 bh * NC chunks = 1024 blocks (4/CU, 16 waves/CU); block: 256 thr.
__global__ __launch_bounds__(256, 4) void k_attn(
    const float* __restrict__ feat, const __bf16* __restrict__ ws_q,
    float* __restrict__ attn_g, __bf16* __restrict__ part, float* __restrict__ zbuf)
{
    const int bh = blockIdx.x >> 4;
    const int nc = blockIdx.x & 15;
    const int b = bh >> 1, h = bh & 1;
    const int tid = threadIdx.x;
    const int lane = tid & 63;
    const int w = tid >> 6;
    const int l15 = lane & 15, g = lane >> 4;
    const int t0 = w * 16;
    const int rot = (int)(blockIdx.x * 3) & 7;   // de-phase subtile walk

    __shared__ __bf16 kT[SS * KTP];     // 16KB transposed [s][c], xor-swizzled
    __shared__ __bf16 P[64 * PP];       // 5KB

    // ---- q fragments: once, straight from global (L2-hot) ----
    bf16x8 afr[8];
    {
        const __bf16* qb = ws_q + ((size_t)bh * 64 + t0 + l15) * 256 + g * 8;
        #pragma unroll
        for (int kk = 0; kk < 8; ++kk)
            afr[kk] = *(const bf16x8*)(qb + kk * 32);
    }

    f32x4 acc[16];
    #pragma unroll
    for (int i = 0; i < 16; ++i) { acc[i][0]=0.f; acc[i][1]=0.f; acc[i][2]=0.f; acc[i][3]=0.f; }
    float zp[4] = {0.f, 0.f, 0.f, 0.f};

    // per-thread global src: c = w*64 + ct*16 + l15, s = nc*SCHUNK + sse*SS + g*8 + [0,8)
    const float* fsrc = feat + ((size_t)b * 512 + (size_t)h * 256) * 4096
                      + (size_t)(w * 64 + l15) * 4096 + nc * SCHUNK + g * 8;

    float4 f4[8];
    {
        const float* p0 = fsrc + rot * SS;      // subtile (ss=0 -> sse=rot)
        #pragma unroll
        for (int ct = 0; ct < 4; ++ct) {
            f4[2*ct]   = *(const float4*)(p0 + (size_t)ct * 16 * 4096);
            f4[2*ct+1] = *(const float4*)(p0 + (size_t)ct * 16 * 4096 + 4);
        }
    }

    bf16x8 kreg[4];

    #pragma unroll 1
    for (int ss = 0; ss < NSUB; ++ss) {
        const int sse = (ss + rot) & 7;
        lds_barrier();                     // B1: prev S's P visible; prev kT reads done
        // ---- AV-GEMM(ss-1): A from shared P, B from registers ----
        if (ss > 0) {
            #pragma unroll
            for (int tt = 0; tt < 4; ++tt) {
                const bf16x8 pa = *(const bf16x8*)&P[(tt * 16 + l15) * PP + g * 8];
                #pragma unroll
                for (int ct = 0; ct < 4; ++ct)
                    acc[tt * 4 + ct] = MFMA(pa, kreg[ct], acc[tt * 4 + ct], 0, 0, 0);
            }
        }
        // ---- stage kT(sse) + kreg(sse) from f4 ----
        #pragma unroll
        for (int ct = 0; ct < 4; ++ct) {
            const float4 a = f4[2*ct], c4 = f4[2*ct+1];
            bf16x8 kv;
            kv[0]=(__bf16)a.x;  kv[1]=(__bf16)a.y;  kv[2]=(__bf16)a.z;  kv[3]=(__bf16)a.w;
            kv[4]=(__bf16)c4.x; kv[5]=(__bf16)c4.y; kv[6]=(__bf16)c4.z; kv[7]=(__bf16)c4.w;
            kreg[ct] = kv;
            const int c = w * 64 + ct * 16 + l15;
            #pragma unroll
            for (int j = 0; j < 8; ++j) {
                const int s = g * 8 + j;
                kT[s * KTP + (c ^ ((s & 15) << 3))] = kv[j];
            }
        }
        // ---- issue next subtile's loads (stay in flight across raw barriers) ----
        if (ss < NSUB - 1) {
            const float* p2 = fsrc + ((ss + 1 + rot) & 7) * SS;
            #pragma unroll
            for (int ct = 0; ct < 4; ++ct) {
                f4[2*ct]   = *(const float4*)(p2 + (size_t)ct * 16 * 4096);
                f4[2*ct+1] = *(const float4*)(p2 + (size_t)ct * 16 * 4096 + 4);
            }
        }
        lds_barrier();                     // B2: kT(sse) ready; AV(ss-1) P-reads done
        // ---- S-GEMM(sse): wave w owns t rows [t0, t0+16), all 32 s ----
        const int sw = nc * SCHUNK + sse * SS;
        #pragma unroll
        for (int nt = 0; nt < 2; ++nt) {
            f32x4 d; d[0]=0.f; d[1]=0.f; d[2]=0.f; d[3]=0.f;
            #pragma unroll
            for (int kk = 0; kk < 8; ++kk) {
                const int cc = kk * 32 + g * 8;
                const bf16x8 bfr = *(const bf16x8*)&kT[(nt * 16 + l15) * KTP + (cc ^ (l15 << 3))];
                d = MFMA(afr[kk], bfr, d, 0, 0, 0);
            }
            #pragma unroll
            for (int r = 0; r < 4; ++r) {
                const int t = t0 + g * 4 + r;
                const float sv = d[r] * 0.0625f;
                attn_g[((size_t)bh * 64 + t) * 4096 + sw + nt * 16 + l15] = sv;
                const float p = __expf(sv);
                zp[r] += p;
                P[t * PP + nt * 16 + l15] = (__bf16)p;
            }
        }
    }
    lds_barrier();                         // last P visible
    // ---- final AV ----
    #pragma unroll
    for (int tt = 0; tt < 4; ++tt) {
        const bf16x8 pa = *(const bf16x8*)&P[(tt * 16 + l15) * PP + g * 8];
        #pragma unroll
        for (int ct = 0; ct < 4; ++ct)
            acc[tt * 4 + ct] = MFMA(pa, kreg[ct], acc[tt * 4 + ct], 0, 0, 0);
    }

    // ---- epilogue: write AV partials (bf16) + z partials ----
    const size_t pbase = (size_t)(bh * NC + nc) * 64 * 256;
    #pragma unroll
    for (int tt = 0; tt < 4; ++tt)
        #pragma unroll
        for (int ct = 0; ct < 4; ++ct)
            #pragma unroll
            for (int r = 0; r < 4; ++r)
                part[pbase + (size_t)(tt * 16 + g * 4 + r) * 256 + w * 64 + ct * 16 + l15]
                    = (__bf16)acc[tt * 4 + ct][r];
    #pragma unroll
    for (int r = 0; r < 4; ++r) {
        float z = zp[r];
        z += __shfl_xor(z, 1); z += __shfl_xor(z, 2);
        z += __shfl_xor(z, 4); z += __shfl_xor(z, 8);
        if (l15 == 0) zbuf[(size_t)(bh * NC + nc) * 64 + t0 + g * 4 + r] = z;
    }
}

// ---------------- K3: combine partials, proj, residual, LayerNorm ----------------
__global__ __launch_bounds__(128) void k_post(
    const float* __restrict__ tokens, const float* __restrict__ proj_w,
    const float* __restrict__ proj_b, const float* __restrict__ ln_w,
    const float* __restrict__ ln_b, const __bf16* __restrict__ part,
    const float* __restrict__ zbuf, float* __restrict__ out_tok)
{
    const int t = blockIdx.x >> 3;
    const int b0 = (blockIdx.x & 7) * 4;
    const int d = threadIdx.x;
    __shared__ float av[4][512];
    __shared__ float Zs[4][2];
    __shared__ float red[2][4][2];

    #pragma unroll
    for (int bb = 0; bb < 4; ++bb) {
        const int b = b0 + bb;
        #pragma unroll
        for (int i = 0; i < 4; ++i) {
            const int c = d + 128 * i;
            const int bh = b * 2 + (c >> 8), cc = c & 255;
            float s = 0.f;
            #pragma unroll
            for (int nc = 0; nc < NC; ++nc)
                s += (float)part[((size_t)(bh * NC + nc) * 64 + t) * 256 + cc];
            av[bb][c] = s;
        }
    }
    if (d < 8) {
        const int bb = d >> 1, hh = d & 1;
        const int bh = (b0 + bb) * 2 + hh;
        float z = 0.f;
        for (int nc = 0; nc < NC; ++nc) z += zbuf[(size_t)(bh * NC + nc) * 64 + t];
        Zs[bb][hh] = z;
    }
    __syncthreads();
    #pragma unroll
    for (int bb = 0; bb < 4; ++bb) {
        const float rz0 = 1.f / Zs[bb][0], rz1 = 1.f / Zs[bb][1];
        #pragma unroll
        for (int i = 0; i < 4; ++i) {
            const int c = d + 128 * i;
            av[bb][c] *= (c < 256) ? rz0 : rz1;
        }
    }
    __syncthreads();

    const float pb = proj_b[d];
    float acc4[4] = {pb, pb, pb, pb};
    const float* wr = proj_w + (size_t)d * 512;
    #pragma unroll 4
    for (int k = 0; k < 512; k += 4) {
        const float4 w4 = *(const float4*)(wr + k);
        #pragma unroll
        for (int bb = 0; bb < 4; ++bb) {
            const float4 a4 = *(const float4*)&av[bb][k];
            acc4[bb] += a4.x * w4.x + a4.y * w4.y + a4.z * w4.z + a4.w * w4.w;
        }
    }
    float r[4], s1[4], s2[4];
    #pragma unroll
    for (int bb = 0; bb < 4; ++bb) {
        r[bb] = tokens[((size_t)t * 32 + b0 + bb) * 128 + d] + acc4[bb];
        s1[bb] = r[bb]; s2[bb] = r[bb] * r[bb];
    }
    #pragma unroll
    for (int o = 1; o < 64; o <<= 1)
        #pragma unroll
        for (int bb = 0; bb < 4; ++bb) {
            s1[bb] += __shfl_xor(s1[bb], o);
            s2[bb] += __shfl_xor(s2[bb], o);
        }
    const int wv = d >> 6;
    if ((d & 63) == 0)
        #pragma unroll
        for (int bb = 0; bb < 4; ++bb) { red[0][bb][wv] = s1[bb]; red[1][bb][wv] = s2[bb]; }
    __syncthreads();
    #pragma unroll
    for (int bb = 0; bb < 4; ++bb) {
        const float mean = (red[0][bb][0] + red[0][bb][1]) * (1.f / 128.f);
        const float ex2  = (red[1][bb][0] + red[1][bb][1]) * (1.f / 128.f);
        const float var = ex2 - mean * mean;
        out_tok[((size_t)t * 32 + b0 + bb) * 128 + d] =
            (r[bb] - mean) * rsqrtf(var + 1e-5f) * ln_w[d] + ln_b[d];
    }
}

extern "C" void kernel_launch(void* const* d_in, const int* in_sizes, int n_in,
                              void* d_out, int out_size, void* d_ws, size_t ws_size,
                              hipStream_t stream) {
    const float* features = (const float*)d_in[0];
    const float* tokens   = (const float*)d_in[1];
    const float* q_w      = (const float*)d_in[2];
    const float* q_b      = (const float*)d_in[3];
    const float* proj_w   = (const float*)d_in[4];
    const float* proj_b   = (const float*)d_in[5];
    const float* ln_w     = (const float*)d_in[6];
    const float* ln_b     = (const float*)d_in[7];

    float* out = (float*)d_out;
    float* out_attn = out + (size_t)64 * 32 * 128;       // tok first, then attn

    __bf16* ws_q = (__bf16*)d_ws;                        // 2 MB
    __bf16* part = (__bf16*)((char*)d_ws + (size_t)2 * 1024 * 1024);   // 33.5 MB
    float* zbuf = (float*)((char*)d_ws + (size_t)40 * 1024 * 1024);    // 256 KB

    k_qproj<<<512, 128, 0, stream>>>(tokens, q_w, q_b, ws_q);
    k_attn<<<64 * NC, 256, 0, stream>>>(features, ws_q, out_attn, part, zbuf);
    k_post<<<512, 128, 0, stream>>>(tokens, proj_w, proj_b, ln_w, ln_b, part, zbuf, out);
}

// Round 9
// 295.342 us; speedup vs baseline: 1.4056x; 1.4056x over previous
//
#include <hip/hip_runtime.h>
#include <stdint.h>
#include <stddef.h>

typedef __attribute__((ext_vector_type(8))) __bf16 bf16x8;
typedef __attribute__((ext_vector_type(4))) float f32x4;

#define NC 8          // s-chunks per (b,h)
#define SCHUNK 512
#define SS 64         // s-subtile: 256B per row per phase = HBM-granule clean
#define NSUB 8        // SCHUNK/SS
#define KTP 256       // kT row pitch (proven layout)
#define PP 72         // P row pitch (64 + 8 pad)

#define MFMA __builtin_amdgcn_mfma_f32_16x16x32_bf16

// Raw barrier WITHOUT vmcnt(0) drain: orders LDS traffic only, leaves
// prefetched global loads in flight (R5's __syncthreads drain was its killer).
__device__ __forceinline__ void lds_barrier() {
    __builtin_amdgcn_sched_barrier(0);
    asm volatile("s_waitcnt lgkmcnt(0)" ::: "memory");
    __builtin_amdgcn_s_barrier();
    __builtin_amdgcn_sched_barrier(0);
}

// ---------------- K1: q projection -> bf16 q[bh][t][ch] in ws ----------------
__global__ __launch_bounds__(128) void k_qproj(
    const float* __restrict__ tokens, const float* __restrict__ q_w,
    const float* __restrict__ q_b, __bf16* __restrict__ ws_q)
{
    const int t = blockIdx.x >> 3;
    const int b0 = (blockIdx.x & 7) * 4;
    const int d = threadIdx.x;
    __shared__ float tok[4][128];
    #pragma unroll
    for (int j = 0; j < 4; ++j)
        tok[j][d] = tokens[((size_t)t * 32 + b0 + j) * 128 + d];
    __syncthreads();
    #pragma unroll
    for (int i = 0; i < 4; ++i) {
        const int c = d + 128 * i;
        const float* wr = q_w + (size_t)c * 128;
        const float qb = q_b[c];
        float acc[4] = {qb, qb, qb, qb};
        #pragma unroll 4
        for (int k = 0; k < 128; k += 4) {
            const float4 w4 = *(const float4*)(wr + k);
            #pragma unroll
            for (int j = 0; j < 4; ++j) {
                const float4 t4 = *(const float4*)&tok[j][k];
                acc[j] += t4.x * w4.x + t4.y * w4.y + t4.z * w4.z + t4.w * w4.w;
            }
        }
        const int h = c >> 8, cc = c & 255;
        #pragma unroll
        for (int j = 0; j < 4; ++j)
            ws_q[(size_t)(((b0 + j) * 2 + h) * 64 + t) * 256 + cc] = (__bf16)acc[j];
    }
}

// ---------------- K2: fused QK^T -> S (out) -> exp -> partial AV ----------------
// grid: 64 bh * NC chunks = 512 blocks (2/CU); block: 256 threads (4 waves)
// SS=64: every per-row global read/write is a 256B-aligned 256B segment
// (no HBM granule waste). Drain-free barriers keep prefetch in flight.
__global__ __launch_bounds__(256, 2) void k_attn(
    const float* __restrict__ feat, const __bf16* __restrict__ ws_q,
    float* __restrict__ attn_g, __bf16* __restrict__ part, float* __restrict__ zbuf)
{
    const int bh = blockIdx.x >> 3;
    const int nc = blockIdx.x & 7;
    const int b = bh >> 1, h = bh & 1;
    const int tid = threadIdx.x;
    const int lane = tid & 63;
    const int w = tid >> 6;
    const int l15 = lane & 15, g = lane >> 4;
    const int t0 = w * 16;
    const int rot = (int)(blockIdx.x * 3) & 7;   // de-phase subtile walk

    __shared__ __bf16 kT[SS * KTP];     // 32KB transposed [s][c], xor-swizzled
    __shared__ __bf16 P[64 * PP];       // 9KB

    // ---- q fragments: once, straight from global (L2-hot) ----
    bf16x8 afr[8];
    {
        const __bf16* qb = ws_q + ((size_t)bh * 64 + t0 + l15) * 256 + g * 8;
        #pragma unroll
        for (int kk = 0; kk < 8; ++kk)
            afr[kk] = *(const bf16x8*)(qb + kk * 32);
    }

    f32x4 acc[16];
    #pragma unroll
    for (int i = 0; i < 16; ++i) { acc[i][0]=0.f; acc[i][1]=0.f; acc[i][2]=0.f; acc[i][3]=0.f; }
    float zp[4] = {0.f, 0.f, 0.f, 0.f};

    // per-thread global src: c = w*64 + ct*16 + l15, s = nc*SCHUNK + sse*SS + ks*32 + g*8
    const float* fsrc = feat + ((size_t)b * 512 + (size_t)h * 256) * 4096
                      + (size_t)(w * 64 + l15) * 4096 + nc * SCHUNK + g * 8;

    float4 f4[16];
    {
        const float* p0 = fsrc + rot * SS;
        #pragma unroll
        for (int ct = 0; ct < 4; ++ct)
            #pragma unroll
            for (int ks = 0; ks < 2; ++ks) {
                f4[ct*4 + ks*2 + 0] = *(const float4*)(p0 + (size_t)ct * 16 * 4096 + ks * 32);
                f4[ct*4 + ks*2 + 1] = *(const float4*)(p0 + (size_t)ct * 16 * 4096 + ks * 32 + 4);
            }
    }

    bf16x8 kreg[8];   // [ct][ks]

    #pragma unroll 1
    for (int ss = 0; ss < NSUB; ++ss) {
        const int sse = (ss + rot) & 7;
        lds_barrier();                     // B1: prev S done; P(prev) visible
        // ---- AV-GEMM(prev): A from shared P, B from registers ----
        if (ss > 0) {
            #pragma unroll
            for (int tt = 0; tt < 4; ++tt)
                #pragma unroll
                for (int ks = 0; ks < 2; ++ks) {
                    const bf16x8 pa = *(const bf16x8*)&P[(tt * 16 + l15) * PP + ks * 32 + g * 8];
                    #pragma unroll
                    for (int ct = 0; ct < 4; ++ct)
                        acc[tt * 4 + ct] = MFMA(pa, kreg[ct*2 + ks], acc[tt * 4 + ct], 0, 0, 0);
                }
        }
        // ---- stage kT(sse) + kreg(sse) from f4 ----
        #pragma unroll
        for (int ct = 0; ct < 4; ++ct)
            #pragma unroll
            for (int ks = 0; ks < 2; ++ks) {
                const float4 a = f4[ct*4 + ks*2], c4 = f4[ct*4 + ks*2 + 1];
                bf16x8 kv;
                kv[0]=(__bf16)a.x;  kv[1]=(__bf16)a.y;  kv[2]=(__bf16)a.z;  kv[3]=(__bf16)a.w;
                kv[4]=(__bf16)c4.x; kv[5]=(__bf16)c4.y; kv[6]=(__bf16)c4.z; kv[7]=(__bf16)c4.w;
                kreg[ct*2 + ks] = kv;
                const int c = w * 64 + ct * 16 + l15;
                #pragma unroll
                for (int j = 0; j < 8; ++j) {
                    const int s = ks * 32 + g * 8 + j;
                    kT[s * KTP + (c ^ ((s & 15) << 3))] = kv[j];
                }
            }
        // ---- issue next subtile's loads (stay in flight across raw barriers) ----
        if (ss < NSUB - 1) {
            const float* p2 = fsrc + ((ss + 1 + rot) & 7) * SS;
            #pragma unroll
            for (int ct = 0; ct < 4; ++ct)
                #pragma unroll
                for (int ks = 0; ks < 2; ++ks) {
                    f4[ct*4 + ks*2 + 0] = *(const float4*)(p2 + (size_t)ct * 16 * 4096 + ks * 32);
                    f4[ct*4 + ks*2 + 1] = *(const float4*)(p2 + (size_t)ct * 16 * 4096 + ks * 32 + 4);
                }
        }
        lds_barrier();                     // B2: kT(sse) ready; AV P-reads done
        // ---- S-GEMM(sse): wave w owns t rows [t0, t0+16), all 64 s ----
        const int sw = nc * SCHUNK + sse * SS;
        #pragma unroll
        for (int nt = 0; nt < 4; ++nt) {
            f32x4 d; d[0]=0.f; d[1]=0.f; d[2]=0.f; d[3]=0.f;
            #pragma unroll
            for (int kk = 0; kk < 8; ++kk) {
                const int cc = kk * 32 + g * 8;
                const bf16x8 bfr = *(const bf16x8*)&kT[(nt * 16 + l15) * KTP + (cc ^ (l15 << 3))];
                d = MFMA(afr[kk], bfr, d, 0, 0, 0);
            }
            #pragma unroll
            for (int r = 0; r < 4; ++r) {
                const int t = t0 + g * 4 + r;
                const float sv = d[r] * 0.0625f;
                attn_g[((size_t)bh * 64 + t) * 4096 + sw + nt * 16 + l15] = sv;
                const float p = __expf(sv);
                zp[r] += p;
                P[t * PP + nt * 16 + l15] = (__bf16)p;
            }
        }
    }
    lds_barrier();                         // last P visible
    // ---- final AV ----
    #pragma unroll
    for (int tt = 0; tt < 4; ++tt)
        #pragma unroll
        for (int ks = 0; ks < 2; ++ks) {
            const bf16x8 pa = *(const bf16x8*)&P[(tt * 16 + l15) * PP + ks * 32 + g * 8];
            #pragma unroll
            for (int ct = 0; ct < 4; ++ct)
                acc[tt * 4 + ct] = MFMA(pa, kreg[ct*2 + ks], acc[tt * 4 + ct], 0, 0, 0);
        }

    // ---- epilogue: write AV partials (bf16) + z partials ----
    const size_t pbase = (size_t)(bh * NC + nc) * 64 * 256;
    #pragma unroll
    for (int tt = 0; tt < 4; ++tt)
        #pragma unroll
        for (int ct = 0; ct < 4; ++ct)
            #pragma unroll
            for (int r = 0; r < 4; ++r)
                part[pbase + (size_t)(tt * 16 + g * 4 + r) * 256 + w * 64 + ct * 16 + l15]
                    = (__bf16)acc[tt * 4 + ct][r];
    #pragma unroll
    for (int r = 0; r < 4; ++r) {
        float z = zp[r];
        z += __shfl_xor(z, 1); z += __shfl_xor(z, 2);
        z += __shfl_xor(z, 4); z += __shfl_xor(z, 8);
        if (l15 == 0) zbuf[(size_t)(bh * NC + nc) * 64 + t0 + g * 4 + r] = z;
    }
}

// ---------------- K3: combine partials, proj, residual, LayerNorm ----------------
__global__ __launch_bounds__(128) void k_post(
    const float* __restrict__ tokens, const float* __restrict__ proj_w,
    const float* __restrict__ proj_b, const float* __restrict__ ln_w,
    const float* __restrict__ ln_b, const __bf16* __restrict__ part,
    const float* __restrict__ zbuf, float* __restrict__ out_tok)
{
    const int t = blockIdx.x >> 3;
    const int b0 = (blockIdx.x & 7) * 4;
    const int d = threadIdx.x;
    __shared__ float av[4][512];
    __shared__ float Zs[4][2];
    __shared__ float red[2][4][2];

    #pragma unroll
    for (int bb = 0; bb < 4; ++bb) {
        const int b = b0 + bb;
        #pragma unroll
        for (int i = 0; i < 4; ++i) {
            const int c = d + 128 * i;
            const int bh = b * 2 + (c >> 8), cc = c & 255;
            float s = 0.f;
            #pragma unroll
            for (int nc = 0; nc < NC; ++nc)
                s += (float)part[((size_t)(bh * NC + nc) * 64 + t) * 256 + cc];
            av[bb][c] = s;
        }
    }
    if (d < 8) {
        const int bb = d >> 1, hh = d & 1;
        const int bh = (b0 + bb) * 2 + hh;
        float z = 0.f;
        for (int nc = 0; nc < NC; ++nc) z += zbuf[(size_t)(bh * NC + nc) * 64 + t];
        Zs[bb][hh] = z;
    }
    __syncthreads();
    #pragma unroll
    for (int bb = 0; bb < 4; ++bb) {
        const float rz0 = 1.f / Zs[bb][0], rz1 = 1.f / Zs[bb][1];
        #pragma unroll
        for (int i = 0; i < 4; ++i) {
            const int c = d + 128 * i;
            av[bb][c] *= (c < 256) ? rz0 : rz1;
        }
    }
    __syncthreads();

    const float pb = proj_b[d];
    float acc4[4] = {pb, pb, pb, pb};
    const float* wr = proj_w + (size_t)d * 512;
    #pragma unroll 4
    for (int k = 0; k < 512; k += 4) {
        const float4 w4 = *(const float4*)(wr + k);
        #pragma unroll
        for (int bb = 0; bb < 4; ++bb) {
            const float4 a4 = *(const float4*)&av[bb][k];
            acc4[bb] += a4.x * w4.x + a4.y * w4.y + a4.z * w4.z + a4.w * w4.w;
        }
    }
    float r[4], s1[4], s2[4];
    #pragma unroll
    for (int bb = 0; bb < 4; ++bb) {
        r[bb] = tokens[((size_t)t * 32 + b0 + bb) * 128 + d] + acc4[bb];
        s1[bb] = r[bb]; s2[bb] = r[bb] * r[bb];
    }
    #pragma unroll
    for (int o = 1; o < 64; o <<= 1)
        #pragma unroll
        for (int bb = 0; bb < 4; ++bb) {
            s1[bb] += __shfl_xor(s1[bb], o);
            s2[bb] += __shfl_xor(s2[bb], o);
        }
    const int wv = d >> 6;
    if ((d & 63) == 0)
        #pragma unroll
        for (int bb = 0; bb < 4; ++bb) { red[0][bb][wv] = s1[bb]; red[1][bb][wv] = s2[bb]; }
    __syncthreads();
    #pragma unroll
    for (int bb = 0; bb < 4; ++bb) {
        const float mean = (red[0][bb][0] + red[0][bb][1]) * (1.f / 128.f);
        const float ex2  = (red[1][bb][0] + red[1][bb][1]) * (1.f / 128.f);
        const float var = ex2 - mean * mean;
        out_tok[((size_t)t * 32 + b0 + bb) * 128 + d] =
            (r[bb] - mean) * rsqrtf(var + 1e-5f) * ln_w[d] + ln_b[d];
    }
}

extern "C" void kernel_launch(void* const* d_in, const int* in_sizes, int n_in,
                              void* d_out, int out_size, void* d_ws, size_t ws_size,
                              hipStream_t stream) {
    const float* features = (const float*)d_in[0];
    const float* tokens   = (const float*)d_in[1];
    const float* q_w      = (const float*)d_in[2];
    const float* q_b      = (const float*)d_in[3];
    const float* proj_w   = (const float*)d_in[4];
    const float* proj_b   = (const float*)d_in[5];
    const float* ln_w     = (const float*)d_in[6];
    const float* ln_b     = (const float*)d_in[7];

    float* out = (float*)d_out;
    float* out_attn = out + (size_t)64 * 32 * 128;       // tok first, then attn

    __bf16* ws_q = (__bf16*)d_ws;                        // 2 MB
    __bf16* part = (__bf16*)((char*)d_ws + (size_t)2 * 1024 * 1024);  // 16.8 MB
    float* zbuf = (float*)((char*)d_ws + (size_t)20 * 1024 * 1024);   // 128 KB

    k_qproj<<<512, 128, 0, stream>>>(tokens, q_w, q_b, ws_q);
    k_attn<<<64 * NC, 256, 0, stream>>>(features, ws_q, out_attn, part, zbuf);
    k_post<<<512, 128, 0, stream>>>(tokens, proj_w, proj_b, ln_w, ln_b, part, zbuf, out);
}

// Round 10
// 132.309 us; speedup vs baseline: 3.1377x; 2.2322x over previous
//
#include <hip/hip_runtime.h>
#include <stdint.h>
#include <stddef.h>

typedef __attribute__((ext_vector_type(8))) __bf16 bf16x8;
typedef __attribute__((ext_vector_type(4))) float f32x4;

#define NC 8          // s-chunks per (b,h)
#define SCHUNK 512
#define SS 32         // s-subtile
#define NSUB 16       // SCHUNK/SS
#define KTP 256       // kT row pitch (proven layout)
#define PP 40         // P row pitch (32 + 8 pad)
#define SLP 72        // Sld row pitch (2 slots of 32 + 8 pad)
#define PBP 264       // part-bounce row pitch (256 + 8 pad)

#define MFMA __builtin_amdgcn_mfma_f32_16x16x32_bf16

// Raw barrier WITHOUT vmcnt(0) drain: orders LDS traffic only, leaves
// prefetched global loads in flight.
__device__ __forceinline__ void lds_barrier() {
    __builtin_amdgcn_sched_barrier(0);
    asm volatile("s_waitcnt lgkmcnt(0)" ::: "memory");
    __builtin_amdgcn_s_barrier();
    __builtin_amdgcn_sched_barrier(0);
}

// ---------------- K1: q projection -> bf16 q[bh][t][ch] in ws ----------------
__global__ __launch_bounds__(128) void k_qproj(
    const float* __restrict__ tokens, const float* __restrict__ q_w,
    const float* __restrict__ q_b, __bf16* __restrict__ ws_q)
{
    const int t = blockIdx.x >> 3;
    const int b0 = (blockIdx.x & 7) * 4;
    const int d = threadIdx.x;
    __shared__ float tok[4][128];
    #pragma unroll
    for (int j = 0; j < 4; ++j)
        tok[j][d] = tokens[((size_t)t * 32 + b0 + j) * 128 + d];
    __syncthreads();
    #pragma unroll
    for (int i = 0; i < 4; ++i) {
        const int c = d + 128 * i;
        const float* wr = q_w + (size_t)c * 128;
        const float qb = q_b[c];
        float acc[4] = {qb, qb, qb, qb};
        #pragma unroll 4
        for (int k = 0; k < 128; k += 4) {
            const float4 w4 = *(const float4*)(wr + k);
            #pragma unroll
            for (int j = 0; j < 4; ++j) {
                const float4 t4 = *(const float4*)&tok[j][k];
                acc[j] += t4.x * w4.x + t4.y * w4.y + t4.z * w4.z + t4.w * w4.w;
            }
        }
        const int h = c >> 8, cc = c & 255;
        #pragma unroll
        for (int j = 0; j < 4; ++j)
            ws_q[(size_t)(((b0 + j) * 2 + h) * 64 + t) * 256 + cc] = (__bf16)acc[j];
    }
}

// ---------------- K2: fused QK^T -> S (out) -> exp -> partial AV ----------------
// grid: 64 bh * NC = 512 blocks (2/CU); block: 256 threads (4 waves)
// All global WRITES are full-256B-granule coalesced (S via LDS double-slot
// flush, partials via LDS bounce) to kill RMW write amplification
// (R8/R9 counters: WRITE 2.3-6.7x unique).
__global__ __launch_bounds__(256, 2) void k_attn(
    const float* __restrict__ feat, const __bf16* __restrict__ ws_q,
    float* __restrict__ attn_g, __bf16* __restrict__ part, float* __restrict__ zbuf)
{
    const int bh = blockIdx.x >> 3;
    const int nc = blockIdx.x & 7;
    const int b = bh >> 1, h = bh & 1;
    const int tid = threadIdx.x;
    const int lane = tid & 63;
    const int w = tid >> 6;
    const int l15 = lane & 15, g = lane >> 4;
    const int t0 = w * 16;

    __shared__ __bf16 kT[SS * KTP];     // 16KB transposed [s][c], xor-swizzled
    __shared__ __bf16 P[64 * PP];       // 5KB
    __shared__ float Sld[64 * SLP];     // 18KB fp32 S, 2 subtile slots
    __shared__ __bf16 pb[64 * PBP];     // 33KB part bounce

    // flush-thread mapping: row = tid>>2, quarter q = tid&3
    const int frow = tid >> 2, fq = tid & 3;
    float* attn_row = attn_g + ((size_t)bh * 64 + frow) * 4096 + nc * SCHUNK;

    // ---- q fragments: once, straight from global (L2-hot) ----
    bf16x8 afr[8];
    {
        const __bf16* qb = ws_q + ((size_t)bh * 64 + t0 + l15) * 256 + g * 8;
        #pragma unroll
        for (int kk = 0; kk < 8; ++kk)
            afr[kk] = *(const bf16x8*)(qb + kk * 32);
    }

    f32x4 acc[16];
    #pragma unroll
    for (int i = 0; i < 16; ++i) { acc[i][0]=0.f; acc[i][1]=0.f; acc[i][2]=0.f; acc[i][3]=0.f; }
    float zp[4] = {0.f, 0.f, 0.f, 0.f};

    // per-thread global src: c = w*64 + ct*16 + l15, s = nc*SCHUNK + ss*SS + g*8
    const float* fsrc = feat + ((size_t)b * 512 + (size_t)h * 256) * 4096
                      + (size_t)(w * 64 + l15) * 4096 + nc * SCHUNK + g * 8;

    float4 f4[8];
    #pragma unroll
    for (int ct = 0; ct < 4; ++ct) {
        f4[2*ct]   = *(const float4*)(fsrc + (size_t)ct * 16 * 4096);
        f4[2*ct+1] = *(const float4*)(fsrc + (size_t)ct * 16 * 4096 + 4);
    }

    bf16x8 kreg[4];

    #pragma unroll 1
    for (int ss = 0; ss < NSUB; ++ss) {
        lds_barrier();                     // B1: prev S (LDS) visible; P(prev) visible
        // ---- flush S pair (ss-2, ss-1) as full 256B/row segments ----
        if ((ss & 1) == 0 && ss > 0) {
            const int pr = (ss >> 1) - 1;
            #pragma unroll
            for (int j = 0; j < 4; ++j) {
                const f32x4 v = *(const f32x4*)&Sld[frow * SLP + fq * 4 + j * 16];
                *(f32x4*)(attn_row + pr * 64 + fq * 4 + j * 16) = v;
            }
        }
        // ---- AV-GEMM(ss-1): A from shared P, B from registers ----
        if (ss > 0) {
            #pragma unroll
            for (int tt = 0; tt < 4; ++tt) {
                const bf16x8 pa = *(const bf16x8*)&P[(tt * 16 + l15) * PP + g * 8];
                #pragma unroll
                for (int ct = 0; ct < 4; ++ct)
                    acc[tt * 4 + ct] = MFMA(pa, kreg[ct], acc[tt * 4 + ct], 0, 0, 0);
            }
        }
        // ---- stage kT(ss) + kreg(ss) from f4 ----
        #pragma unroll
        for (int ct = 0; ct < 4; ++ct) {
            const float4 a = f4[2*ct], c4 = f4[2*ct+1];
            bf16x8 kv;
            kv[0]=(__bf16)a.x;  kv[1]=(__bf16)a.y;  kv[2]=(__bf16)a.z;  kv[3]=(__bf16)a.w;
            kv[4]=(__bf16)c4.x; kv[5]=(__bf16)c4.y; kv[6]=(__bf16)c4.z; kv[7]=(__bf16)c4.w;
            kreg[ct] = kv;
            const int c = w * 64 + ct * 16 + l15;
            #pragma unroll
            for (int j = 0; j < 8; ++j) {
                const int s = g * 8 + j;
                kT[s * KTP + (c ^ ((s & 15) << 3))] = kv[j];
            }
        }
        // ---- issue next subtile's loads (stay in flight across raw barriers) ----
        if (ss < NSUB - 1) {
            const float* p2 = fsrc + (ss + 1) * SS;
            #pragma unroll
            for (int ct = 0; ct < 4; ++ct) {
                f4[2*ct]   = *(const float4*)(p2 + (size_t)ct * 16 * 4096);
                f4[2*ct+1] = *(const float4*)(p2 + (size_t)ct * 16 * 4096 + 4);
            }
        }
        lds_barrier();                     // B2: kT(ss) ready; AV P-reads + S-flush done
        // ---- S-GEMM(ss): wave w owns t rows [t0, t0+16), all 32 s ----
        const int slot = (ss & 1) * 32;
        #pragma unroll
        for (int nt = 0; nt < 2; ++nt) {
            f32x4 d; d[0]=0.f; d[1]=0.f; d[2]=0.f; d[3]=0.f;
            #pragma unroll
            for (int kk = 0; kk < 8; ++kk) {
                const int cc = kk * 32 + g * 8;
                const bf16x8 bfr = *(const bf16x8*)&kT[(nt * 16 + l15) * KTP + (cc ^ (l15 << 3))];
                d = MFMA(afr[kk], bfr, d, 0, 0, 0);
            }
            #pragma unroll
            for (int r = 0; r < 4; ++r) {
                const int t = t0 + g * 4 + r;
                const float sv = d[r] * 0.0625f;
                Sld[t * SLP + slot + nt * 16 + l15] = sv;
                const float p = __expf(sv);
                zp[r] += p;
                P[t * PP + nt * 16 + l15] = (__bf16)p;
            }
        }
    }
    lds_barrier();                         // last S pair + last P visible
    // ---- flush final S pair (14,15) ----
    {
        #pragma unroll
        for (int j = 0; j < 4; ++j) {
            const f32x4 v = *(const f32x4*)&Sld[frow * SLP + fq * 4 + j * 16];
            *(f32x4*)(attn_row + 7 * 64 + fq * 4 + j * 16) = v;
        }
    }
    // ---- final AV(15) ----
    #pragma unroll
    for (int tt = 0; tt < 4; ++tt) {
        const bf16x8 pa = *(const bf16x8*)&P[(tt * 16 + l15) * PP + g * 8];
        #pragma unroll
        for (int ct = 0; ct < 4; ++ct)
            acc[tt * 4 + ct] = MFMA(pa, kreg[ct], acc[tt * 4 + ct], 0, 0, 0);
    }

    // ---- epilogue: AV partials -> LDS bounce -> coalesced bf16 writes ----
    #pragma unroll
    for (int tt = 0; tt < 4; ++tt)
        #pragma unroll
        for (int ct = 0; ct < 4; ++ct)
            #pragma unroll
            for (int r = 0; r < 4; ++r)
                pb[(tt * 16 + g * 4 + r) * PBP + w * 64 + ct * 16 + l15]
                    = (__bf16)acc[tt * 4 + ct][r];
    #pragma unroll
    for (int r = 0; r < 4; ++r) {
        float z = zp[r];
        z += __shfl_xor(z, 1); z += __shfl_xor(z, 2);
        z += __shfl_xor(z, 4); z += __shfl_xor(z, 8);
        if (l15 == 0) zbuf[(size_t)(bh * NC + nc) * 64 + t0 + g * 4 + r] = z;
    }
    lds_barrier();                         // pb complete
    {
        __bf16* prow = part + (size_t)(bh * NC + nc) * 64 * 256 + (size_t)frow * 256;
        #pragma unroll
        for (int j = 0; j < 8; ++j) {
            const bf16x8 v = *(const bf16x8*)&pb[frow * PBP + fq * 8 + j * 32];
            *(bf16x8*)(prow + fq * 8 + j * 32) = v;
        }
    }
}

// ---------------- K3: combine partials, proj, residual, LayerNorm ----------------
__global__ __launch_bounds__(128) void k_post(
    const float* __restrict__ tokens, const float* __restrict__ proj_w,
    const float* __restrict__ proj_b, const float* __restrict__ ln_w,
    const float* __restrict__ ln_b, const __bf16* __restrict__ part,
    const float* __restrict__ zbuf, float* __restrict__ out_tok)
{
    const int t = blockIdx.x >> 3;
    const int b0 = (blockIdx.x & 7) * 4;
    const int d = threadIdx.x;
    __shared__ float av[4][512];
    __shared__ float Zs[4][2];
    __shared__ float red[2][4][2];

    #pragma unroll
    for (int bb = 0; bb < 4; ++bb) {
        const int b = b0 + bb;
        #pragma unroll
        for (int i = 0; i < 4; ++i) {
            const int c = d + 128 * i;
            const int bh = b * 2 + (c >> 8), cc = c & 255;
            float s = 0.f;
            #pragma unroll
            for (int nc = 0; nc < NC; ++nc)
                s += (float)part[((size_t)(bh * NC + nc) * 64 + t) * 256 + cc];
            av[bb][c] = s;
        }
    }
    if (d < 8) {
        const int bb = d >> 1, hh = d & 1;
        const int bh = (b0 + bb) * 2 + hh;
        float z = 0.f;
        for (int nc = 0; nc < NC; ++nc) z += zbuf[(size_t)(bh * NC + nc) * 64 + t];
        Zs[bb][hh] = z;
    }
    __syncthreads();
    #pragma unroll
    for (int bb = 0; bb < 4; ++bb) {
        const float rz0 = 1.f / Zs[bb][0], rz1 = 1.f / Zs[bb][1];
        #pragma unroll
        for (int i = 0; i < 4; ++i) {
            const int c = d + 128 * i;
            av[bb][c] *= (c < 256) ? rz0 : rz1;
        }
    }
    __syncthreads();

    const float pb = proj_b[d];
    float acc4[4] = {pb, pb, pb, pb};
    const float* wr = proj_w + (size_t)d * 512;
    #pragma unroll 4
    for (int k = 0; k < 512; k += 4) {
        const float4 w4 = *(const float4*)(wr + k);
        #pragma unroll
        for (int bb = 0; bb < 4; ++bb) {
            const float4 a4 = *(const float4*)&av[bb][k];
            acc4[bb] += a4.x * w4.x + a4.y * w4.y + a4.z * w4.z + a4.w * w4.w;
        }
    }
    float r[4], s1[4], s2[4];
    #pragma unroll
    for (int bb = 0; bb < 4; ++bb) {
        r[bb] = tokens[((size_t)t * 32 + b0 + bb) * 128 + d] + acc4[bb];
        s1[bb] = r[bb]; s2[bb] = r[bb] * r[bb];
    }
    #pragma unroll
    for (int o = 1; o < 64; o <<= 1)
        #pragma unroll
        for (int bb = 0; bb < 4; ++bb) {
            s1[bb] += __shfl_xor(s1[bb], o);
            s2[bb] += __shfl_xor(s2[bb], o);
        }
    const int wv = d >> 6;
    if ((d & 63) == 0)
        #pragma unroll
        for (int bb = 0; bb < 4; ++bb) { red[0][bb][wv] = s1[bb]; red[1][bb][wv] = s2[bb]; }
    __syncthreads();
    #pragma unroll
    for (int bb = 0; bb < 4; ++bb) {
        const float mean = (red[0][bb][0] + red[0][bb][1]) * (1.f / 128.f);
        const float ex2  = (red[1][bb][0] + red[1][bb][1]) * (1.f / 128.f);
        const float var = ex2 - mean * mean;
        out_tok[((size_t)t * 32 + b0 + bb) * 128 + d] =
            (r[bb] - mean) * rsqrtf(var + 1e-5f) * ln_w[d] + ln_b[d];
    }
}

extern "C" void kernel_launch(void* const* d_in, const int* in_sizes, int n_in,
                              void* d_out, int out_size, void* d_ws, size_t ws_size,
                              hipStream_t stream) {
    const float* features = (const float*)d_in[0];
    const float* tokens   = (const float*)d_in[1];
    const float* q_w      = (const float*)d_in[2];
    const float* q_b      = (const float*)d_in[3];
    const float* proj_w   = (const float*)d_in[4];
    const float* proj_b   = (const float*)d_in[5];
    const float* ln_w     = (const float*)d_in[6];
    const float* ln_b     = (const float*)d_in[7];

    float* out = (float*)d_out;
    float* out_attn = out + (size_t)64 * 32 * 128;       // tok first, then attn

    __bf16* ws_q = (__bf16*)d_ws;                        // 2 MB
    __bf16* part = (__bf16*)((char*)d_ws + (size_t)2 * 1024 * 1024);  // 16.8 MB
    float* zbuf = (float*)((char*)d_ws + (size_t)20 * 1024 * 1024);   // 128 KB

    k_qproj<<<512, 128, 0, stream>>>(tokens, q_w, q_b, ws_q);
    k_attn<<<64 * NC, 256, 0, stream>>>(features, ws_q, out_attn, part, zbuf);
    k_post<<<512, 128, 0, stream>>>(tokens, proj_w, proj_b, ln_w, ln_b, part, zbuf, out);
}